// Round 3
// baseline (469.782 us; speedup 1.0000x reference)
//
#include <hip/hip_runtime.h>
#include <hip/hip_fp16.h>
#include <math.h>

#define T_DIM 4096
#define MOL_N 2048
#define DESC_N 6
#define NSOL_N 5
#define H_DIM 2048
#define DBLK 2054
#define D_IN_N 12325
#define GK 2048

typedef _Float16 f16x8 __attribute__((ext_vector_type(8)));
typedef float f32x4 __attribute__((ext_vector_type(4)));

// tanh-form GELU as x * sigmoid(1.5957691x + 0.0713548x^3).
__device__ __forceinline__ float gelu_f(float x) {
    float v = x * (1.5957691f + 0.0713548f * x * x);
    float e = __expf(-v);
    return x / (1.0f + e);
}

// ---- Kernel 1a: fold layer-0 weights, LDS-staged row version ----
// Each block stages a full 49.3KB W0 row into LDS via 13x global_load_lds
// w16 (aligned contiguous 52KB stream per block -> best DRAM behavior, zero
// VALU on the stream), then computes the 6 chunk-dots from LDS with
// lane-consecutive conflict-free ds_read_b32 + L2-hot scalar x loads.
__global__ __launch_bounds__(256) void fold2_kernel(
    const float* __restrict__ W0f, const float* __restrict__ W0b,
    const float* __restrict__ b0f, const float* __restrict__ b0b,
    const float* __restrict__ mol, const float* __restrict__ sv,
    float* __restrict__ fold_f, float* __restrict__ fold_b)
{
    __shared__ float wrow[13312];     // 53,248 B: holds [A0, A0+13312) dwords
    __shared__ float red[4][6];
    const int tid = threadIdx.x;
    const int wave = tid >> 6, lane = tid & 63;
    const size_t matbytes = (size_t)2048 * D_IN_N * 4;
    char* wrc = (char*)wrow;

    for (int rr = 0; rr < 4; ++rr) {
        const int r = blockIdx.x + rr * 1024;      // 0..4095
        const int z = r >> 11, h = r & 2047;
        const float* __restrict__ W0 = z ? W0b : W0f;
        const float* __restrict__ b0 = z ? b0b : b0f;
        float* __restrict__ fold = z ? fold_b : fold_f;
        const size_t rowdw = (size_t)h * D_IN_N;
        const size_t A0 = rowdw & ~(size_t)3;      // aligned flat dword base
        const int p = (int)(rowdw & 3);            // row phase within LDS
        const size_t A0byte = A0 * 4;
        const char* __restrict__ W0c = (const char*)W0;

        // stage: 13 x 4KB block-iterations, wave-uniform LDS base + lane*16
        #pragma unroll
        for (int j = 0; j < 13; ++j) {
            const size_t off = (size_t)j * 4096 + (size_t)wave * 1024 + (size_t)lane * 16;
            size_t g = A0byte + off;
            if (g + 16 > matbytes) g = A0byte;     // clamp tail of last row
            __builtin_amdgcn_global_load_lds(
                (const __attribute__((address_space(1))) void*)(W0c + g),
                (__attribute__((address_space(3))) void*)(wrc + off), 16, 0, 0);
        }
        asm volatile("s_waitcnt vmcnt(0)" ::: "memory");
        __syncthreads();

        // 6 chunk-dots: chunk s base = 0 (mol) or DBLK*s (solvent s-1)
        float acc[6] = {0.f, 0.f, 0.f, 0.f, 0.f, 0.f};
        #pragma unroll
        for (int s = 0; s < 6; ++s) {
            const int cb = (s == 0) ? 0 : DBLK * s;
            const float* __restrict__ xp = (s == 0) ? mol : (sv + (size_t)(s - 1) * MOL_N);
            #pragma unroll
            for (int q = 0; q < 8; ++q) {
                const int col = tid + q * 256;     // lane-consecutive
                acc[s] += wrow[p + cb + col] * xp[col];
            }
        }
        #pragma unroll
        for (int i = 0; i < 6; ++i) {
            float v = acc[i];
            #pragma unroll
            for (int off = 32; off >= 1; off >>= 1)
                v += __shfl_xor(v, off, 64);
            acc[i] = v;
        }
        if (lane == 0) {
            #pragma unroll
            for (int i = 0; i < 6; ++i) red[wave][i] = acc[i];
        }
        __syncthreads();
        if (tid < 6) {
            float s = red[0][tid] + red[1][tid] + red[2][tid] + red[3][tid];
            if (tid == 0) fold[h] = s + b0[h];
            else fold[(size_t)tid * H_DIM + h] = s;    // u_s at (1+s)H, s=tid-1
        }
        if (tid >= 64 && tid < 70) {
            const int j = tid - 64;
            float w = wrow[p + MOL_N + j];
            #pragma unroll
            for (int s = 1; s <= 5; ++s) w += wrow[p + DBLK * s + MOL_N + j];
            fold[(size_t)(6 + j) * H_DIM + h] = w;
        }
        if (tid == 70) fold[(size_t)12 * H_DIM + h] = wrow[p + D_IN_N - 1];
        __syncthreads();   // protect wrow/red before next row's stage
    }
}

// ---- Kernel 1b: convert W1/W2 (both trunks) fp32 -> fp16, 4 float4/thread ----
__global__ __launch_bounds__(256) void conv_kernel(
    const float* __restrict__ W1f, const float* __restrict__ W2f,
    const float* __restrict__ W1b, const float* __restrict__ W2b,
    _Float16* __restrict__ Wc)
{
    const int b = blockIdx.x;                  // 4096 blocks
    const int z = b >> 10;                     // 1024 blocks per matrix
    const float* __restrict__ src = (z == 0) ? W1f : (z == 1) ? W2f : (z == 2) ? W1b : W2b;
    _Float16* __restrict__ dst = Wc + (size_t)z * H_DIM * H_DIM;
    const int base4 = (b & 1023) * 1024;       // float4 index base
    struct h4 { _Float16 a, b, c, d; };
    #pragma unroll
    for (int k = 0; k < 4; ++k) {
        const int i4 = base4 + k * 256 + threadIdx.x;
        float4 v = ((const float4*)src)[i4];
        h4 o;
        o.a = (_Float16)v.x; o.b = (_Float16)v.y; o.c = (_Float16)v.z; o.d = (_Float16)v.w;
        ((h4*)dst)[i4] = o;
    }
}

// ---- Kernel 2: h0 = gelu(folded layer-0), 4 h per thread, 8B fp16 stores ----
__global__ __launch_bounds__(256) void h0_kernel(
    const float* __restrict__ fold_f, const float* __restrict__ fold_b,
    const float* __restrict__ desc, const float* __restrict__ sol,
    const float* __restrict__ rf,
    _Float16* __restrict__ h0f, _Float16* __restrict__ h0b)
{
    const int z = blockIdx.z;
    const float* __restrict__ fold = z ? fold_b : fold_f;
    _Float16* __restrict__ h0 = z ? h0b : h0f;
    const int hb = blockIdx.x * 1024 + threadIdx.x * 4;
    const int tbase = blockIdx.y * 64;

    float c0a[4], wpa[4], ua[NSOL_N][4], wda[DESC_N][4];
    {
        float4 v = *(const float4*)&fold[hb];
        c0a[0] = v.x; c0a[1] = v.y; c0a[2] = v.z; c0a[3] = v.w;
        v = *(const float4*)&fold[(size_t)12 * H_DIM + hb];
        wpa[0] = v.x; wpa[1] = v.y; wpa[2] = v.z; wpa[3] = v.w;
        #pragma unroll
        for (int s = 0; s < NSOL_N; ++s) {
            v = *(const float4*)&fold[(size_t)(1 + s) * H_DIM + hb];
            ua[s][0] = v.x; ua[s][1] = v.y; ua[s][2] = v.z; ua[s][3] = v.w;
        }
        #pragma unroll
        for (int j = 0; j < DESC_N; ++j) {
            v = *(const float4*)&fold[(size_t)(6 + j) * H_DIM + hb];
            wda[j][0] = v.x; wda[j][1] = v.y; wda[j][2] = v.z; wda[j][3] = v.w;
        }
    }

    struct h4s { _Float16 a, b, c, d; };
    for (int i = 0; i < 64; ++i) {
        const int t = tbase + i;
        float pv;
        if (z == 0) pv = (t == 0) ? 0.5f : rf[t - 1];
        else        pv = (t == T_DIM - 1) ? 0.5f : rf[t + 1];
        float sl[NSOL_N], dc[DESC_N];
        #pragma unroll
        for (int s = 0; s < NSOL_N; ++s) sl[s] = sol[t * NSOL_N + s];
        #pragma unroll
        for (int j = 0; j < DESC_N; ++j) dc[j] = desc[t * DESC_N + j];
        float o[4];
        #pragma unroll
        for (int e = 0; e < 4; ++e) {
            float pre = c0a[e] + wpa[e] * pv;
            #pragma unroll
            for (int s = 0; s < NSOL_N; ++s) pre += ua[s][e] * sl[s];
            #pragma unroll
            for (int j = 0; j < DESC_N; ++j) pre += wda[j][e] * dc[j];
            o[e] = gelu_f(pre);
        }
        h4s ov;
        ov.a = (_Float16)o[0]; ov.b = (_Float16)o[1];
        ov.c = (_Float16)o[2]; ov.d = (_Float16)o[3];
        *(h4s*)&h0[(size_t)t * H_DIM + hb] = ov;
    }
}

// ---- 256x256-tile, 8-wave, BK=32, 4-deep ring pipelined GEMM core ----
// Counted vmcnt(8) keeps 2 tiles (8 loads/thread) in flight across barriers
// (T3+T4). One s_barrier per K-step. Tile k+3 staged into ring slot (k-1)&3,
// whose reads are drained (trailing lgkmcnt(0)) before any wave's next
// barrier -> race-free. Global-source XOR swizzle c^=((r>>1)&3) with linear
// LDS dest gives 2-way (free) bank aliasing on ds_read_b128.
__device__ __forceinline__ void gemm_core256(
    const _Float16* __restrict__ A, const _Float16* __restrict__ W,
    const int m0, const int n0, char* sc, f32x4 (&acc)[8][4])
{
    const int tid = threadIdx.x;
    const int wave = tid >> 6;
    const int lane = tid & 63;
    const int t15 = lane & 15;
    const int quad = lane >> 4;
    const int wr = wave >> 2;   // 0..1 : 128-row half
    const int wc = wave & 3;    // 0..3 : 64-col quarter
    const int poff = (quad ^ ((t15 >> 1) & 3)) * 16;
    const int aoff0 = (wr * 128 + t15) * 64 + poff;
    const int boff0 = 16384 + (wc * 64 + t15) * 64 + poff;

    const _Float16* gsrc[4];
    #pragma unroll
    for (int ld = 0; ld < 4; ++ld) {
        const int j = (ld & 1) * 512 + tid;       // chunk index within A or B
        const int r = j >> 2;                     // row 0..255
        const int c = (j & 3) ^ ((r >> 1) & 3);   // pre-swizzled k-chunk
        gsrc[ld] = ((ld < 2) ? (A + (size_t)(m0 + r) * GK)
                             : (W + (size_t)(n0 + r) * GK)) + c * 8;
    }

    #pragma unroll
    for (int mi = 0; mi < 8; ++mi)
        #pragma unroll
        for (int ni = 0; ni < 4; ++ni)
            acc[mi][ni] = (f32x4){0.f, 0.f, 0.f, 0.f};

#define STAGE_T(kt, b) do { \
    char* _db = sc + (b) * 32768; \
    const int _ko = (kt) * 32; \
    __builtin_amdgcn_global_load_lds((const __attribute__((address_space(1))) void*)(gsrc[0] + _ko), (__attribute__((address_space(3))) void*)(_db + wave * 1024), 16, 0, 0); \
    __builtin_amdgcn_global_load_lds((const __attribute__((address_space(1))) void*)(gsrc[1] + _ko), (__attribute__((address_space(3))) void*)(_db + 8192 + wave * 1024), 16, 0, 0); \
    __builtin_amdgcn_global_load_lds((const __attribute__((address_space(1))) void*)(gsrc[2] + _ko), (__attribute__((address_space(3))) void*)(_db + 16384 + wave * 1024), 16, 0, 0); \
    __builtin_amdgcn_global_load_lds((const __attribute__((address_space(1))) void*)(gsrc[3] + _ko), (__attribute__((address_space(3))) void*)(_db + 24576 + wave * 1024), 16, 0, 0); \
} while (0)

#define COMPUTE_T(b) do { \
    const char* _db = sc + (b) * 32768; \
    f16x8 aF[8], bF[4]; \
    _Pragma("unroll") \
    for (int mi = 0; mi < 8; ++mi) aF[mi] = *(const f16x8*)(_db + aoff0 + mi * 1024); \
    _Pragma("unroll") \
    for (int ni = 0; ni < 4; ++ni) bF[ni] = *(const f16x8*)(_db + boff0 + ni * 1024); \
    __builtin_amdgcn_s_setprio(1); \
    _Pragma("unroll") \
    for (int mi = 0; mi < 8; ++mi) { \
        _Pragma("unroll") \
        for (int ni = 0; ni < 4; ++ni) \
            acc[mi][ni] = __builtin_amdgcn_mfma_f32_16x16x32_f16(aF[mi], bF[ni], acc[mi][ni], 0, 0, 0); \
    } \
    __builtin_amdgcn_s_setprio(0); \
    asm volatile("s_waitcnt lgkmcnt(0)" ::: "memory"); \
} while (0)

    STAGE_T(0, 0); STAGE_T(1, 1); STAGE_T(2, 2);

    #pragma unroll 1
    for (int k4 = 0; k4 < 60; k4 += 4) {
        asm volatile("s_waitcnt vmcnt(8)" ::: "memory");
        __builtin_amdgcn_s_barrier();
        STAGE_T(k4 + 3, 3); COMPUTE_T(0);
        asm volatile("s_waitcnt vmcnt(8)" ::: "memory");
        __builtin_amdgcn_s_barrier();
        STAGE_T(k4 + 4, 0); COMPUTE_T(1);
        asm volatile("s_waitcnt vmcnt(8)" ::: "memory");
        __builtin_amdgcn_s_barrier();
        STAGE_T(k4 + 5, 1); COMPUTE_T(2);
        asm volatile("s_waitcnt vmcnt(8)" ::: "memory");
        __builtin_amdgcn_s_barrier();
        STAGE_T(k4 + 6, 2); COMPUTE_T(3);
    }
    asm volatile("s_waitcnt vmcnt(8)" ::: "memory");
    __builtin_amdgcn_s_barrier();
    STAGE_T(63, 3); COMPUTE_T(0);
    asm volatile("s_waitcnt vmcnt(8)" ::: "memory");
    __builtin_amdgcn_s_barrier();
    COMPUTE_T(1);
    asm volatile("s_waitcnt vmcnt(4)" ::: "memory");
    __builtin_amdgcn_s_barrier();
    COMPUTE_T(2);
    asm volatile("s_waitcnt vmcnt(0)" ::: "memory");
    __builtin_amdgcn_s_barrier();
    COMPUTE_T(3);

#undef STAGE_T
#undef COMPUTE_T
}

// ---- Kernel 3: GEMM layer-1, C = gelu(A @ W^T + bias), fp16 out ----
__global__ __launch_bounds__(512, 2) void gemm1_kernel(
    const _Float16* __restrict__ Af, const _Float16* __restrict__ Ab,
    const _Float16* __restrict__ Wfp, const _Float16* __restrict__ Wbp,
    const float* __restrict__ bfp, const float* __restrict__ bbp,
    _Float16* __restrict__ Cf, _Float16* __restrict__ Cb)
{
    __shared__ _Float16 smem[65536];   // 128 KiB: 4-slot ring of (A 16K + B 16K)
    char* sc = (char*)smem;
    const int bid = blockIdx.x;
    const int xcd = bid & 7;
    const int slot = bid >> 3;
    const int z = xcd & 1;
    const int q = xcd >> 1;
    const int m0 = (q * 4 + (slot & 3)) * 256;
    const int n0 = (slot >> 2) * 256;

    const _Float16* __restrict__ A = z ? Ab : Af;
    const _Float16* __restrict__ W = z ? Wbp : Wfp;
    const float* __restrict__ bias = z ? bbp : bfp;
    _Float16* __restrict__ C = z ? Cb : Cf;

    f32x4 acc[8][4];
    gemm_core256(A, W, m0, n0, sc, acc);

    const int tid = threadIdx.x;
    const int wave = tid >> 6, lane = tid & 63;
    const int colC = lane & 15, quad = lane >> 4;
    const int wr = wave >> 2, wc = wave & 3;
    #pragma unroll
    for (int ni = 0; ni < 4; ++ni) {
        const int n = n0 + wc * 64 + ni * 16 + colC;
        const float bv = bias[n];
        #pragma unroll
        for (int mi = 0; mi < 8; ++mi) {
            const int mb = m0 + wr * 128 + mi * 16 + quad * 4;
            #pragma unroll
            for (int r = 0; r < 4; ++r)
                C[(size_t)(mb + r) * H_DIM + n] = (_Float16)gelu_f(acc[mi][ni][r] + bv);
        }
    }
}

// ---- Kernel 4: GEMM layer-2 with FUSED output head ----
__global__ __launch_bounds__(512, 2) void gemm_out_kernel(
    const _Float16* __restrict__ Af, const _Float16* __restrict__ Ab,
    const _Float16* __restrict__ Wfp, const _Float16* __restrict__ Wbp,
    const float* __restrict__ bfp, const float* __restrict__ bbp,
    const float* __restrict__ Wof, const float* __restrict__ Wob,
    float* __restrict__ partial)
{
    __shared__ _Float16 smem[65536];
    char* sc = (char*)smem;
    const int bid = blockIdx.x;
    const int xcd = bid & 7;
    const int slot = bid >> 3;
    const int z = xcd & 1;
    const int q = xcd >> 1;
    const int m0 = (q * 4 + (slot & 3)) * 256;
    const int n0 = (slot >> 2) * 256;

    const _Float16* __restrict__ A = z ? Ab : Af;
    const _Float16* __restrict__ W = z ? Wbp : Wfp;
    const float* __restrict__ bias = z ? bbp : bfp;
    const float* __restrict__ Wo = z ? Wob : Wof;

    f32x4 acc[8][4];
    gemm_core256(A, W, m0, n0, sc, acc);

    const int tid = threadIdx.x;
    const int wave = tid >> 6, lane = tid & 63;
    const int colC = lane & 15, quad = lane >> 4;
    const int wr = wave >> 2, wc = wave & 3;

    float bv[4], wo[4];
    #pragma unroll
    for (int ni = 0; ni < 4; ++ni) {
        const int n = n0 + wc * 64 + ni * 16 + colC;
        bv[ni] = bias[n];
        wo[ni] = Wo[n];
    }

    __syncthreads();                 // all waves done with smem ring
    float* red = (float*)sc;         // [4 wc][256 rows]
    #pragma unroll
    for (int mi = 0; mi < 8; ++mi) {
        #pragma unroll
        for (int r = 0; r < 4; ++r) {
            float s = 0.f;
            #pragma unroll
            for (int ni = 0; ni < 4; ++ni)
                s += gelu_f(acc[mi][ni][r] + bv[ni]) * wo[ni];
            s += __shfl_xor(s, 1, 64);
            s += __shfl_xor(s, 2, 64);
            s += __shfl_xor(s, 4, 64);
            s += __shfl_xor(s, 8, 64);
            if (colC == 0)
                red[wc * 256 + wr * 128 + mi * 16 + quad * 4 + r] = s;
        }
    }
    __syncthreads();
    if (tid < 256) {
        float v = red[tid] + red[256 + tid] + red[512 + tid] + red[768 + tid];
        const int n_tile = slot >> 2;
        partial[((size_t)z * 8 + n_tile) * T_DIM + m0 + tid] = v;
    }
}

// ---- Kernel 5: finalize — sum n-tile partials + bias + clip ----
__global__ __launch_bounds__(256) void finalize_kernel(
    const float* __restrict__ partial,
    const float* __restrict__ bof, const float* __restrict__ bob,
    float* __restrict__ out)
{
    const int idx = blockIdx.x * 256 + threadIdx.x;   // 0..8191
    const int z = idx >> 12;
    const int row = idx & 4095;
    float v = z ? bob[0] : bof[0];
    #pragma unroll
    for (int nt = 0; nt < 8; ++nt)
        v += partial[((size_t)z * 8 + nt) * T_DIM + row];
    v = fminf(fmaxf(v, 1e-4f), 1.0f - 1e-4f);
    out[idx] = v;
}

extern "C" void kernel_launch(void* const* d_in, const int* in_sizes, int n_in,
                              void* d_out, int out_size, void* d_ws, size_t ws_size,
                              hipStream_t stream)
{
    (void)in_sizes; (void)n_in; (void)out_size; (void)ws_size;
    const float* mol = (const float*)d_in[0];
    const float* sol = (const float*)d_in[1];
    const float* desc = (const float*)d_in[2];
    const float* rf  = (const float*)d_in[3];
    const float* sv  = (const float*)d_in[4];
    const float* Wf0 = (const float*)d_in[5];
    const float* Wf1 = (const float*)d_in[6];
    const float* Wf2 = (const float*)d_in[7];
    const float* Wof = (const float*)d_in[8];
    const float* Wb0 = (const float*)d_in[9];
    const float* Wb1 = (const float*)d_in[10];
    const float* Wb2 = (const float*)d_in[11];
    const float* Wob = (const float*)d_in[12];
    const float* bf0 = (const float*)d_in[13];
    const float* bf1 = (const float*)d_in[14];
    const float* bf2 = (const float*)d_in[15];
    const float* bof = (const float*)d_in[16];
    const float* bb0 = (const float*)d_in[17];
    const float* bb1 = (const float*)d_in[18];
    const float* bb2 = (const float*)d_in[19];
    const float* bob = (const float*)d_in[20];
    float* out = (float*)d_out;

    char* ws = (char*)d_ws;
    float* fold_f = (float*)(ws + 0);          // 13*2048*4 = 106496 B
    float* fold_b = (float*)(ws + 131072);
    _Float16* Wc = (_Float16*)(ws + 262144);   // 4 x 2048*2048 fp16 = 33554432 B
    const size_t WSZ = (size_t)H_DIM * H_DIM;
    _Float16* W1f_c = Wc;
    _Float16* W2f_c = Wc + WSZ;
    _Float16* W1b_c = Wc + 2 * WSZ;
    _Float16* W2b_c = Wc + 3 * WSZ;
    const size_t HSZ = (size_t)T_DIM * H_DIM;  // 16777216 B fp16 each
    _Float16* h0f = (_Float16*)(ws + 33816576);
    _Float16* h0b = h0f + HSZ;
    _Float16* h1f = (_Float16*)(ws + 33816576 + 2 * 16777216);
    _Float16* h1b = h1f + HSZ;
    float* partial = (float*)(ws + 33816576);  // reuse h0f region (dead after gemm1); 256 KB
    // total ws use: 33816576 + 4*16777216 = 100,925,440 B

    fold2_kernel<<<dim3(1024), 256, 0, stream>>>(Wf0, Wb0, bf0, bb0, mol, sv, fold_f, fold_b);
    conv_kernel<<<dim3(4096), 256, 0, stream>>>(Wf1, Wf2, Wb1, Wb2, Wc);
    h0_kernel<<<dim3(2, 64, 2), 256, 0, stream>>>(fold_f, fold_b, desc, sol, rf, h0f, h0b);
    gemm1_kernel<<<dim3(256), 512, 0, stream>>>(h0f, h0b, W1f_c, W1b_c, bf1, bb1, h1f, h1b);
    gemm_out_kernel<<<dim3(256), 512, 0, stream>>>(h1f, h1b, W2f_c, W2b_c, bf2, bb2, Wof, Wob, partial);
    finalize_kernel<<<dim3(32), 256, 0, stream>>>(partial, bof, bob, out);
}